// Round 1
// baseline (512.526 us; speedup 1.0000x reference)
//
#include <hip/hip_runtime.h>
#include <stdint.h>

// LSTM cell fused as one bf16-MFMA GEMM: M=65536, N=1024 (4 gates x 256), K=512 (x||h)
// gates[b][n] = sum_k A[b][k] * W[n][k] + bi[n] + bh[n],  n = gate*256 + h
#define B_DIM 65536
#define H_OUT 16777216   // B_DIM*256, offset of c_new in d_out

typedef __attribute__((ext_vector_type(8))) short short8;
typedef __attribute__((ext_vector_type(4))) float f32x4;

struct F4 { float v[4]; };

__device__ __forceinline__ unsigned short f2bf(float f) {
  unsigned int u = __builtin_bit_cast(unsigned int, f);
  u += 0x7FFFu + ((u >> 16) & 1u);          // RNE
  return (unsigned short)(u >> 16);
}

__device__ __forceinline__ float sigf(float x) { return 1.0f / (1.0f + __expf(-x)); }
__device__ __forceinline__ float tanh_fast(float x) {
  float a = fabsf(x);
  float e = __expf(-2.0f * a);              // e in (0,1], no overflow
  float t = (1.0f - e) / (1.0f + e);
  return x < 0.0f ? -t : t;
}

typedef const __attribute__((address_space(1))) unsigned int* as1_cuintp;
typedef __attribute__((address_space(3))) unsigned int* as3_uintp;
__device__ __forceinline__ void llds16(const void* g, void* l) {
  // async global->LDS, 16B per lane; LDS dest is wave-uniform base + lane*16
  __builtin_amdgcn_global_load_lds((as1_cuintp)g, (as3_uintp)l, 16, 0, 0);
}

// ---- prep: fp32 -> bf16 staging into workspace -----------------------------
__global__ void prep_a(const float* __restrict__ x, const float* __restrict__ h,
                       unsigned short* __restrict__ A) {
  unsigned idx = blockIdx.x * 256u + threadIdx.x;   // [0, B*128)
  unsigned b = idx >> 7, cth = idx & 127u;          // 128 float4-chunks per row
  const float* src = (cth < 64u) ? (x + (size_t)b * 256u + cth * 4u)
                                 : (h + (size_t)b * 256u + (cth - 64u) * 4u);
  F4 v = *(const F4*)src;
  ushort4 o;
  o.x = f2bf(v.v[0]); o.y = f2bf(v.v[1]); o.z = f2bf(v.v[2]); o.w = f2bf(v.v[3]);
  *(ushort4*)(A + (size_t)b * 512u + cth * 4u) = o;
}

__global__ void prep_w(const float* __restrict__ Wi, const float* __restrict__ Wh,
                       unsigned short* __restrict__ W) {
  unsigned idx = blockIdx.x * 256u + threadIdx.x;   // [0, 1024*128)
  unsigned n = idx >> 7, cth = idx & 127u;
  const float* src = (cth < 64u) ? (Wi + (size_t)n * 256u + cth * 4u)
                                 : (Wh + (size_t)n * 256u + (cth - 64u) * 4u);
  F4 v = *(const F4*)src;
  ushort4 o;
  o.x = f2bf(v.v[0]); o.y = f2bf(v.v[1]); o.z = f2bf(v.v[2]); o.w = f2bf(v.v[3]);
  *(ushort4*)(W + (size_t)n * 512u + cth * 4u) = o;
}

// ---- fused GEMM + LSTM elementwise -----------------------------------------
// grid = (B/128)*8 blocks, 256 threads (4 waves, 2x2 over a 128x128 tile).
// Tile columns c in [0,128): gate k = c>>5, h = h0 + (c&31) -> W row n = k*256+h0+(c&31).
__global__ __launch_bounds__(256, 2) void lstm_gemm(
    const unsigned short* __restrict__ A,   // [B][512] bf16
    const unsigned short* __restrict__ W,   // [1024][512] bf16
    const float* __restrict__ cprev,
    const float* __restrict__ bi, const float* __restrict__ bh,
    float* __restrict__ out) {
  __shared__ union {
    struct { unsigned short A[128 * 32]; unsigned short B[128 * 32]; } st; // 16 KB
    float g[64 * 132];                                                     // 33.8 KB
  } sm;

  const int t = threadIdx.x;
  const int wid = t >> 6, lane = t & 63;
  const int m = lane & 15, q = lane >> 4;
  const int b0 = (int)(blockIdx.x >> 3) * 128;   // 8 consecutive blocks share A rows (L3 reuse)
  const int h0 = (int)(blockIdx.x & 7) * 32;

  // staging: 8KB A-tile + 8KB B-tile per iter = 16 segs of 1KB; wave w owns segs {2w,2w+1} of each
  const int s0 = wid * 2, s1 = wid * 2 + 1;
  const int rA0 = s0 * 16 + (lane >> 2), rA1 = s1 * 16 + (lane >> 2); // tile row / tile col
  const unsigned ch = (unsigned)(lane & 3) * 8u;                      // k-chunk (8 bf16 = 16B)
  const unsigned aOff0 = (unsigned)(b0 + rA0) * 512u + ch;
  const unsigned aOff1 = (unsigned)(b0 + rA1) * 512u + ch;
  const int n0 = ((rA0 >> 5) << 8) + h0 + (rA0 & 31);
  const int n1 = ((rA1 >> 5) << 8) + h0 + (rA1 & 31);
  const unsigned wOff0 = (unsigned)n0 * 512u + ch;
  const unsigned wOff1 = (unsigned)n1 * 512u + ch;

  const int R = (wid >> 1) * 64, Cc = (wid & 1) * 64;

  // accumulators pre-seeded with bias (same col for all 4 regs of a frag)
  f32x4 acc[4][4];
#pragma unroll
  for (int j = 0; j < 4; ++j) {
    int cj = Cc + j * 16 + m;
    int nj = ((cj >> 5) << 8) + h0 + (cj & 31);
    float bv = bi[nj] + bh[nj];
#pragma unroll
    for (int i = 0; i < 4; ++i) { f32x4 z = {bv, bv, bv, bv}; acc[i][j] = z; }
  }

  for (int kt = 0; kt < 16; ++kt) {
    const unsigned k0 = kt * 32u;
    llds16(A + aOff0 + k0, &sm.st.A[s0 * 512]);
    llds16(A + aOff1 + k0, &sm.st.A[s1 * 512]);
    llds16(W + wOff0 + k0, &sm.st.B[s0 * 512]);
    llds16(W + wOff1 + k0, &sm.st.B[s1 * 512]);
    __syncthreads();   // drains vmcnt then barrier
    short8 av[4], bv[4];
#pragma unroll
    for (int i = 0; i < 4; ++i)
      av[i] = *(const short8*)&sm.st.A[(R + i * 16 + m) * 32 + q * 8];
#pragma unroll
    for (int j = 0; j < 4; ++j)
      bv[j] = *(const short8*)&sm.st.B[(Cc + j * 16 + m) * 32 + q * 8];
#pragma unroll
    for (int i = 0; i < 4; ++i)
#pragma unroll
      for (int j = 0; j < 4; ++j)
        acc[i][j] = __builtin_amdgcn_mfma_f32_16x16x32_bf16(av[i], bv[j], acc[i][j], 0, 0, 0);
    __syncthreads();
  }

  // epilogue: two halves of 64 rows through LDS (stride 132 -> 2-way conflicts only)
  const int wr = wid >> 1, wc = wid & 1;
  for (int half = 0; half < 2; ++half) {
    if (wr == half) {
#pragma unroll
      for (int i = 0; i < 4; ++i)
#pragma unroll
        for (int r = 0; r < 4; ++r) {
          int row_l = i * 16 + q * 4 + r;            // C/D: row = (lane>>4)*4 + reg
          float* dst = &sm.g[row_l * 132 + wc * 64 + m];
#pragma unroll
          for (int j = 0; j < 4; ++j) dst[j * 16] = acc[i][j][r];
        }
    }
    __syncthreads();
#pragma unroll
    for (int p = 0; p < 2; ++p) {
      int rl = p * 32 + (t >> 3);
      int hc = (t & 7) * 4;
      int b = b0 + half * 64 + rl;
      const float* gr = &sm.g[rl * 132 + hc];
      F4 gi = *(const F4*)(gr);
      F4 gf = *(const F4*)(gr + 32);
      F4 gg = *(const F4*)(gr + 64);
      F4 go = *(const F4*)(gr + 96);
      F4 cv = *(const F4*)(cprev + (size_t)b * 256 + h0 + hc);
      F4 hn, cn;
#pragma unroll
      for (int u = 0; u < 4; ++u) {
        float iv = sigf(gi.v[u]);
        float fv = sigf(gf.v[u]);
        float gv = tanh_fast(gg.v[u]);
        float ov = sigf(go.v[u]);
        float cnew = fv * cv.v[u] + iv * gv;
        cn.v[u] = cnew;
        hn.v[u] = ov * tanh_fast(cnew);
      }
      *(F4*)(out + (size_t)b * 256 + h0 + hc) = hn;
      *(F4*)(out + (size_t)H_OUT + (size_t)b * 256 + h0 + hc) = cn;
    }
    __syncthreads();   // protect gbuf before next half's writes
  }
}

// ---- fallback (tiny workspace): correct but slow fp32 path -----------------
__global__ void lstm_naive(const float* __restrict__ x, const float* __restrict__ h,
                           const float* __restrict__ c,
                           const float* __restrict__ Wi, const float* __restrict__ Wh,
                           const float* __restrict__ bi, const float* __restrict__ bh,
                           float* __restrict__ out) {
  int gid = blockIdx.x * 256 + threadIdx.x;
  int b = gid >> 8, hh = gid & 255;
  float a0 = bi[hh] + bh[hh];
  float a1 = bi[256 + hh] + bh[256 + hh];
  float a2 = bi[512 + hh] + bh[512 + hh];
  float a3 = bi[768 + hh] + bh[768 + hh];
  const float* xr = x + (size_t)b * 256;
  const float* hr = h + (size_t)b * 256;
  const float* w0 = Wi + (size_t)hh * 256;
  const float* w1 = Wh + (size_t)hh * 256;
  for (int i = 0; i < 256; ++i) {
    float xv = xr[i];
    a0 += xv * w0[i];
    a1 += xv * w0[65536 + i];
    a2 += xv * w0[131072 + i];
    a3 += xv * w0[196608 + i];
  }
  for (int i = 0; i < 256; ++i) {
    float hv = hr[i];
    a0 += hv * w1[i];
    a1 += hv * w1[65536 + i];
    a2 += hv * w1[131072 + i];
    a3 += hv * w1[196608 + i];
  }
  float iv = sigf(a0), fv = sigf(a1), gv = tanh_fast(a2), ov = sigf(a3);
  float cn = fv * c[gid] + iv * gv;
  out[gid] = ov * tanh_fast(cn);
  out[H_OUT + gid] = cn;
}

extern "C" void kernel_launch(void* const* d_in, const int* in_sizes, int n_in,
                              void* d_out, int out_size, void* d_ws, size_t ws_size,
                              hipStream_t stream) {
  const float* x  = (const float*)d_in[0];
  const float* h  = (const float*)d_in[1];
  const float* c  = (const float*)d_in[2];
  const float* Wi = (const float*)d_in[3];
  const float* Wh = (const float*)d_in[4];
  const float* bi = (const float*)d_in[5];
  const float* bh = (const float*)d_in[6];
  float* out = (float*)d_out;

  const size_t needA = (size_t)B_DIM * 512 * 2;   // 64 MB bf16 A = x||h
  const size_t needW = (size_t)1024 * 512 * 2;    // 1 MB bf16 W = Wi||Wh
  if (ws_size >= needA + needW) {
    unsigned short* Abf = (unsigned short*)d_ws;
    unsigned short* Wbf = (unsigned short*)((char*)d_ws + needA);
    hipLaunchKernelGGL(prep_a, dim3(B_DIM * 128 / 256), dim3(256), 0, stream, x, h, Abf);
    hipLaunchKernelGGL(prep_w, dim3(1024 * 128 / 256), dim3(256), 0, stream, Wi, Wh, Wbf);
    hipLaunchKernelGGL(lstm_gemm, dim3((B_DIM / 128) * 8), dim3(256), 0, stream,
                       Abf, Wbf, c, bi, bh, out);
  } else {
    hipLaunchKernelGGL(lstm_naive, dim3(B_DIM), dim3(256), 0, stream,
                       x, h, c, Wi, Wh, bi, bh, out);
  }
}

// Round 2
// 417.305 us; speedup vs baseline: 1.2282x; 1.2282x over previous
//
#include <hip/hip_runtime.h>
#include <stdint.h>

// LSTM cell as one bf16-MFMA GEMM: M=65536, N=1024 (4 gates x 256), K=512 (x||h)
// Tile col map: c in [0,128): gate=(c>>4)&3, h = h0 + (c&15) + 16*(c>>6)
//  -> wave frag j == gate, lane m == h column  => register-only LSTM epilogue.
#define B_DIM 65536
#define HOFF  16777216   // B_DIM*256, offset of c_new in d_out

typedef __attribute__((ext_vector_type(8))) short short8;
typedef __attribute__((ext_vector_type(8))) unsigned short ushort8_t;
typedef __attribute__((ext_vector_type(4))) float f32x4;

__device__ __forceinline__ unsigned short f2bf(float f) {
  unsigned int u = __builtin_bit_cast(unsigned int, f);
  u += 0x7FFFu + ((u >> 16) & 1u);          // RNE
  return (unsigned short)(u >> 16);
}
__device__ __forceinline__ float sigf(float x) { return 1.0f / (1.0f + __expf(-x)); }
__device__ __forceinline__ float tanh_fast(float x) {
  float a = fabsf(x);
  float e = __expf(-2.0f * a);
  float t = (1.0f - e) / (1.0f + e);
  return x < 0.0f ? -t : t;
}

typedef const __attribute__((address_space(1))) unsigned int* as1p;
typedef __attribute__((address_space(3))) unsigned int* as3p;
__device__ __forceinline__ void llds16(const unsigned short* g, unsigned short* l) {
  __builtin_amdgcn_global_load_lds((as1p)g, (as3p)l, 16, 0, 0);
}

// ---- prep: fp32 -> bf16, 8 elems/thread, 16B-aligned loads/stores ----------
__global__ void prep_a(const float* __restrict__ x, const float* __restrict__ h,
                       ushort8_t* __restrict__ A8) {
  unsigned o = blockIdx.x * 256u + threadIdx.x;   // [0, B*64)
  unsigned b = o >> 6, c8 = o & 63u;
  const float* src = (c8 < 32u) ? x + (size_t)b * 256u + c8 * 8u
                                : h + (size_t)b * 256u + (c8 - 32u) * 8u;
  float4 v0 = *(const float4*)src;
  float4 v1 = *(const float4*)(src + 4);
  ushort8_t p;
  p[0] = f2bf(v0.x); p[1] = f2bf(v0.y); p[2] = f2bf(v0.z); p[3] = f2bf(v0.w);
  p[4] = f2bf(v1.x); p[5] = f2bf(v1.y); p[6] = f2bf(v1.z); p[7] = f2bf(v1.w);
  A8[o] = p;                                      // = A[b*512 + c8*8]
}

__global__ void prep_w(const float* __restrict__ Wi, const float* __restrict__ Wh,
                       ushort8_t* __restrict__ W8) {
  unsigned o = blockIdx.x * 256u + threadIdx.x;   // [0, 1024*64)
  unsigned n = o >> 6, c8 = o & 63u;
  const float* src = (c8 < 32u) ? Wi + (size_t)n * 256u + c8 * 8u
                                : Wh + (size_t)n * 256u + (c8 - 32u) * 8u;
  float4 v0 = *(const float4*)src;
  float4 v1 = *(const float4*)(src + 4);
  ushort8_t p;
  p[0] = f2bf(v0.x); p[1] = f2bf(v0.y); p[2] = f2bf(v0.z); p[3] = f2bf(v0.w);
  p[4] = f2bf(v1.x); p[5] = f2bf(v1.y); p[6] = f2bf(v1.z); p[7] = f2bf(v1.w);
  W8[o] = p;
}

// ---- fused GEMM + register LSTM epilogue -----------------------------------
// grid = (B/128)*8, 256 threads (4 waves, 2x2 over 128x128 tile), BK=32.
// LDS tile layout [row][4 slots x 16B], slot = chunk ^ ((row>>1)&3)  (XOR swizzle
// applied via per-lane GLOBAL addresses so global_load_lds LDS side stays linear).
// Frag read bank-group = 4*(row&1) + (q^((m>>1)&3)) -> all 8 groups, 2-way = free.
__global__ __launch_bounds__(256, 4) void lstm_gemm(
    const unsigned short* __restrict__ A,   // [B][512] bf16
    const unsigned short* __restrict__ W,   // [1024][512] bf16
    const float* __restrict__ cprev,
    const float* __restrict__ bi, const float* __restrict__ bh,
    float* __restrict__ out) {
  __shared__ unsigned short sA[128 * 32];   // 8 KB
  __shared__ unsigned short sB[128 * 32];   // 8 KB

  const int t = threadIdx.x;
  const int wid = t >> 6, lane = t & 63;
  const int m = lane & 15, q = lane >> 4;
  const int b0 = (int)(blockIdx.x >> 3) * 128;
  const int h0 = (int)(blockIdx.x & 7) * 32;
  const int R = (wid >> 1) * 64, Cc = (wid & 1) * 64;
  const int hcol = h0 + ((Cc >> 6) << 4) + m;     // this lane's h column

  // staging: 16 segs of 1KB (16 rows x 64B); wave owns A segs {2w,2w+1}, B same
  const int l4 = lane >> 2;
  const int sg0 = wid * 2, sg1 = wid * 2 + 1;
  const int r0 = sg0 * 16 + l4, r1 = sg1 * 16 + l4;       // tile row / tile col
  const int ck = ((lane & 3) ^ ((l4 >> 1) & 3)) * 8;      // swizzled k-chunk (ushorts)
  const unsigned aO0 = (unsigned)(b0 + r0) * 512u + (unsigned)ck;
  const unsigned aO1 = (unsigned)(b0 + r1) * 512u + (unsigned)ck;
  const int n0 = (((r0 >> 4) & 3) << 8) + h0 + (r0 & 15) + ((r0 >> 6) << 4);
  const int n1 = (((r1 >> 4) & 3) << 8) + h0 + (r1 & 15) + ((r1 >> 6) << 4);
  const unsigned wO0 = (unsigned)n0 * 512u + (unsigned)ck;
  const unsigned wO1 = (unsigned)n1 * 512u + (unsigned)ck;
  unsigned short* dA0 = &sA[sg0 * 512];
  unsigned short* dA1 = &sA[sg1 * 512];
  unsigned short* dB0 = &sB[sg0 * 512];
  unsigned short* dB1 = &sB[sg1 * 512];

  const int swz = (q ^ ((m >> 1) & 3)) * 8;       // frag-read slot offset (ushorts)

  // accumulators pre-seeded with bias (col = m fixed per lane; rows share bias)
  f32x4 acc[4][4];
#pragma unroll
  for (int j = 0; j < 4; ++j) {
    float bv = bi[(j << 8) + hcol] + bh[(j << 8) + hcol];
    f32x4 z = {bv, bv, bv, bv};
#pragma unroll
    for (int i = 0; i < 4; ++i) acc[i][j] = z;
  }

  for (int kt = 0; kt < 16; ++kt) {
    const unsigned k0 = kt * 32u;
    llds16(A + aO0 + k0, dA0);
    llds16(A + aO1 + k0, dA1);
    llds16(W + wO0 + k0, dB0);
    llds16(W + wO1 + k0, dB1);
    __syncthreads();
    short8 av[4], bv[4];
#pragma unroll
    for (int i = 0; i < 4; ++i)
      av[i] = *(const short8*)&sA[(R + i * 16 + m) * 32 + swz];
#pragma unroll
    for (int j = 0; j < 4; ++j)
      bv[j] = *(const short8*)&sB[(Cc + j * 16 + m) * 32 + swz];
#pragma unroll
    for (int i = 0; i < 4; ++i)
#pragma unroll
      for (int j = 0; j < 4; ++j)
        acc[i][j] = __builtin_amdgcn_mfma_f32_16x16x32_bf16(av[i], bv[j], acc[i][j], 0, 0, 0);
    __syncthreads();
  }

  // register-only epilogue: lane m holds gates j=0..3 for rows q*4+r of each i-block
  const float* cp = cprev + hcol;
  float* oh = out + hcol;
  float* oc = out + HOFF + hcol;
#pragma unroll
  for (int i = 0; i < 4; ++i) {
    const int br = b0 + R + i * 16 + (q << 2);
    float cv[4];
#pragma unroll
    for (int r = 0; r < 4; ++r) cv[r] = cp[(size_t)(br + r) << 8];
#pragma unroll
    for (int r = 0; r < 4; ++r) {
      float iv = sigf(acc[i][0][r]);
      float fv = sigf(acc[i][1][r]);
      float gv = tanh_fast(acc[i][2][r]);
      float ov = sigf(acc[i][3][r]);
      float cn = fv * cv[r] + iv * gv;
      oh[(size_t)(br + r) << 8] = ov * tanh_fast(cn);
      oc[(size_t)(br + r) << 8] = cn;
    }
  }
}

// ---- fallback (tiny workspace): correct but slow fp32 path -----------------
__global__ void lstm_naive(const float* __restrict__ x, const float* __restrict__ h,
                           const float* __restrict__ c,
                           const float* __restrict__ Wi, const float* __restrict__ Wh,
                           const float* __restrict__ bi, const float* __restrict__ bh,
                           float* __restrict__ out) {
  int gid = blockIdx.x * 256 + threadIdx.x;
  int b = gid >> 8, hh = gid & 255;
  float a0 = bi[hh] + bh[hh];
  float a1 = bi[256 + hh] + bh[256 + hh];
  float a2 = bi[512 + hh] + bh[512 + hh];
  float a3 = bi[768 + hh] + bh[768 + hh];
  const float* xr = x + (size_t)b * 256;
  const float* hr = h + (size_t)b * 256;
  const float* w0 = Wi + (size_t)hh * 256;
  const float* w1 = Wh + (size_t)hh * 256;
  for (int i = 0; i < 256; ++i) {
    float xv = xr[i];
    a0 += xv * w0[i]; a1 += xv * w0[65536 + i];
    a2 += xv * w0[131072 + i]; a3 += xv * w0[196608 + i];
  }
  for (int i = 0; i < 256; ++i) {
    float hv = hr[i];
    a0 += hv * w1[i]; a1 += hv * w1[65536 + i];
    a2 += hv * w1[131072 + i]; a3 += hv * w1[196608 + i];
  }
  float iv = sigf(a0), fv = sigf(a1), gv = tanh_fast(a2), ov = sigf(a3);
  float cn = fv * c[gid] + iv * gv;
  out[gid] = ov * tanh_fast(cn);
  out[HOFF + gid] = cn;
}

extern "C" void kernel_launch(void* const* d_in, const int* in_sizes, int n_in,
                              void* d_out, int out_size, void* d_ws, size_t ws_size,
                              hipStream_t stream) {
  const float* x  = (const float*)d_in[0];
  const float* h  = (const float*)d_in[1];
  const float* c  = (const float*)d_in[2];
  const float* Wi = (const float*)d_in[3];
  const float* Wh = (const float*)d_in[4];
  const float* bi = (const float*)d_in[5];
  const float* bh = (const float*)d_in[6];
  float* out = (float*)d_out;

  const size_t needA = (size_t)B_DIM * 512 * 2;   // 64 MB bf16 A = x||h
  const size_t needW = (size_t)1024 * 512 * 2;    // 1 MB bf16 W
  if (ws_size >= needA + needW) {
    ushort8_t* A8 = (ushort8_t*)d_ws;
    ushort8_t* W8 = (ushort8_t*)((char*)d_ws + needA);
    hipLaunchKernelGGL(prep_a, dim3(B_DIM * 64 / 256), dim3(256), 0, stream, x, h, A8);
    hipLaunchKernelGGL(prep_w, dim3(1024 * 64 / 256), dim3(256), 0, stream, Wi, Wh, W8);
    hipLaunchKernelGGL(lstm_gemm, dim3((B_DIM / 128) * 8), dim3(256), 0, stream,
                       (const unsigned short*)A8, (const unsigned short*)W8,
                       c, bi, bh, out);
  } else {
    hipLaunchKernelGGL(lstm_naive, dim3(B_DIM), dim3(256), 0, stream,
                       x, h, c, Wi, Wh, bi, bh, out);
  }
}